// Round 1
// baseline (843.165 us; speedup 1.0000x reference)
//
#include <hip/hip_runtime.h>
#include <float.h>

#define HEADS 4
#define HID 64
#define HC 256   // HEADS*HID
#define NEG_SLOPE 0.2f
#define EPS 1e-16f

// ---------------------------------------------------------------------------
// Generic tiled fp32 GEMM: C = A[MxK] @ B[KxN] (+bias) (+act)
// act: 0=none, 1=relu, 2=sigmoid. K must be a multiple of 16 (128/256/64 here).
// ---------------------------------------------------------------------------
#define BM 64
#define BN 64
#define BKK 16

__global__ void __launch_bounds__(256) gemm_bias_act(
    const float* __restrict__ A, const float* __restrict__ B,
    const float* __restrict__ bias, float* __restrict__ C,
    int M, int N, int K, int act) {
  __shared__ float As[BKK][BM];
  __shared__ float Bs[BKK][BN];
  int tid = threadIdx.x;
  int tx = tid & 15, ty = tid >> 4;
  int row0 = blockIdx.y * BM, col0 = blockIdx.x * BN;
  float acc[4][4] = {};
  for (int k0 = 0; k0 < K; k0 += BKK) {
    for (int i = tid; i < BM * BKK; i += 256) {
      int r = i >> 4, c = i & 15;
      int gr = row0 + r;
      As[c][r] = (gr < M) ? A[(size_t)gr * K + (k0 + c)] : 0.f;
    }
    for (int i = tid; i < BKK * BN; i += 256) {
      int r = i >> 6, c = i & 63;
      int gc = col0 + c;
      Bs[r][c] = (gc < N) ? B[(size_t)(k0 + r) * N + gc] : 0.f;
    }
    __syncthreads();
#pragma unroll
    for (int kk = 0; kk < BKK; ++kk) {
      float a[4], b[4];
#pragma unroll
      for (int i = 0; i < 4; i++) a[i] = As[kk][ty * 4 + i];
#pragma unroll
      for (int j = 0; j < 4; j++) b[j] = Bs[kk][tx * 4 + j];
#pragma unroll
      for (int i = 0; i < 4; i++)
#pragma unroll
        for (int j = 0; j < 4; j++) acc[i][j] += a[i] * b[j];
    }
    __syncthreads();
  }
#pragma unroll
  for (int i = 0; i < 4; i++) {
    int r = row0 + ty * 4 + i;
    if (r >= M) continue;
#pragma unroll
    for (int j = 0; j < 4; j++) {
      int c = col0 + tx * 4 + j;
      if (c >= N) continue;
      float v = acc[i][j] + (bias ? bias[c] : 0.f);
      if (act == 1) v = fmaxf(v, 0.f);
      else if (act == 2) v = 1.f / (1.f + __expf(-v));
      C[(size_t)r * N + c] = v;
    }
  }
}

// ---------------------------------------------------------------------------
// Attention coefficients: a_s[n,h] = <h[n,h,:], att_src[h,:]>, same for a_d.
// One thread per (node, head).
// ---------------------------------------------------------------------------
__global__ void attn_coef(const float* __restrict__ h,
                          const float* __restrict__ att_s,
                          const float* __restrict__ att_d,
                          float* __restrict__ a_s, float* __restrict__ a_d,
                          int n) {
  int idx = blockIdx.x * 256 + threadIdx.x;
  if (idx >= n * HEADS) return;
  int node = idx >> 2, hd = idx & 3;
  const float* hp = h + (size_t)node * HC + hd * HID;
  const float* ws = att_s + hd * HID;
  const float* wd = att_d + hd * HID;
  float ss = 0.f, sd = 0.f;
#pragma unroll 8
  for (int c = 0; c < HID; ++c) {
    float v = hp[c];
    ss += v * ws[c];
    sd += v * wd[c];
  }
  a_s[idx] = ss;
  a_d[idx] = sd;
}

// ---------------------------------------------------------------------------
// CSR build: degree histogram (self-loop = init 1), block-parallel scan,
// cursor copy, scatter fill.
// ---------------------------------------------------------------------------
__global__ void deg_init(int* __restrict__ deg, int n) {
  int i = blockIdx.x * 256 + threadIdx.x;
  if (i < n) deg[i] = 1;  // self loop
}

__global__ void deg_count(const int* __restrict__ ei, int E, int* __restrict__ deg) {
  int i = blockIdx.x * 256 + threadIdx.x;
  if (i < E) atomicAdd(&deg[ei[E + i]], 1);  // row 1 = dst
}

__global__ void __launch_bounds__(1024) scan_rowstart(
    const int* __restrict__ deg, int* __restrict__ row_start, int n) {
  __shared__ int wave_tot[16];
  __shared__ int carry_s;
  int tid = threadIdx.x;
  int lane = tid & 63, wid = tid >> 6;
  if (tid == 0) { carry_s = 0; row_start[0] = 0; }
  __syncthreads();
  for (int base = 0; base < n; base += 1024) {
    int i = base + tid;
    int v = (i < n) ? deg[i] : 0;
    int s = v;
#pragma unroll
    for (int off = 1; off < 64; off <<= 1) {
      int t = __shfl_up(s, off);
      if (lane >= off) s += t;
    }
    if (lane == 63) wave_tot[wid] = s;
    __syncthreads();
    if (wid == 0) {
      int wv = (lane < 16) ? wave_tot[lane] : 0;
      int ws = wv;
#pragma unroll
      for (int off = 1; off < 16; off <<= 1) {
        int t = __shfl_up(ws, off);
        if (lane >= off) ws += t;
      }
      if (lane < 16) wave_tot[lane] = ws;
    }
    __syncthreads();
    int offset = carry_s + (wid > 0 ? wave_tot[wid - 1] : 0);
    if (i < n) row_start[i + 1] = offset + s;
    __syncthreads();
    if (tid == 0) carry_s += wave_tot[15];
    __syncthreads();
  }
}

__global__ void cursor_copy(const int* __restrict__ row_start, int* __restrict__ cur, int n) {
  int i = blockIdx.x * 256 + threadIdx.x;
  if (i < n) cur[i] = row_start[i];
}

__global__ void csr_fill(const int* __restrict__ ei, int E, int n,
                         int* __restrict__ cur, int* __restrict__ csr_src) {
  int i = blockIdx.x * 256 + threadIdx.x;
  int Etot = E + n;
  if (i >= Etot) return;
  int s, d;
  if (i < E) { s = ei[i]; d = ei[E + i]; }
  else { s = d = i - E; }
  int pos = atomicAdd(&cur[d], 1);
  csr_src[pos] = s;
}

// ---------------------------------------------------------------------------
// GAT aggregation: one wave per destination node, online softmax over its
// incoming edges. Lane t holds channel t of each of the 4 heads.
// out[n,:] = (sum_j exp(e_j - m) * h[src_j]) / (l + EPS) + bias, opt relu.
// ---------------------------------------------------------------------------
__device__ __forceinline__ void online_upd(float e, float hv, float& m, float& l, float& c) {
  if (e > m) {
    float sc = __expf(m - e);
    l *= sc; c *= sc; m = e;
  }
  float p = __expf(e - m);
  l += p; c += p * hv;
}

__global__ void __launch_bounds__(256) gat_aggregate(
    const float* __restrict__ h, const float* __restrict__ a_src,
    const float* __restrict__ a_dst, const int* __restrict__ row_start,
    const int* __restrict__ csr_src, const float* __restrict__ bias,
    float* __restrict__ out, int n, int do_relu) {
  int wid = threadIdx.x >> 6;
  int lane = threadIdx.x & 63;
  int node = (blockIdx.x << 2) + wid;
  if (node >= n) return;
  float ad0 = a_dst[node * 4 + 0], ad1 = a_dst[node * 4 + 1];
  float ad2 = a_dst[node * 4 + 2], ad3 = a_dst[node * 4 + 3];
  float m0 = -FLT_MAX, m1 = -FLT_MAX, m2 = -FLT_MAX, m3 = -FLT_MAX;
  float l0 = 0.f, l1 = 0.f, l2 = 0.f, l3 = 0.f;
  float c0 = 0.f, c1 = 0.f, c2 = 0.f, c3 = 0.f;
  int beg = row_start[node], end = row_start[node + 1];
  for (int e = beg; e < end; ++e) {
    int s = csr_src[e];
    const float* hp = h + (size_t)s * HC;
    float as0 = a_src[s * 4 + 0], as1 = a_src[s * 4 + 1];
    float as2 = a_src[s * 4 + 2], as3 = a_src[s * 4 + 3];
    float h0 = hp[lane], h1 = hp[64 + lane], h2 = hp[128 + lane], h3 = hp[192 + lane];
    float e0 = as0 + ad0; e0 = (e0 > 0.f) ? e0 : NEG_SLOPE * e0;
    float e1 = as1 + ad1; e1 = (e1 > 0.f) ? e1 : NEG_SLOPE * e1;
    float e2 = as2 + ad2; e2 = (e2 > 0.f) ? e2 : NEG_SLOPE * e2;
    float e3 = as3 + ad3; e3 = (e3 > 0.f) ? e3 : NEG_SLOPE * e3;
    online_upd(e0, h0, m0, l0, c0);
    online_upd(e1, h1, m1, l1, c1);
    online_upd(e2, h2, m2, l2, c2);
    online_upd(e3, h3, m3, l3, c3);
  }
  float o0 = c0 / (l0 + EPS) + bias[lane];
  float o1 = c1 / (l1 + EPS) + bias[64 + lane];
  float o2 = c2 / (l2 + EPS) + bias[128 + lane];
  float o3 = c3 / (l3 + EPS) + bias[192 + lane];
  if (do_relu) {
    o0 = fmaxf(o0, 0.f); o1 = fmaxf(o1, 0.f);
    o2 = fmaxf(o2, 0.f); o3 = fmaxf(o3, 0.f);
  }
  float* op = out + (size_t)node * HC;
  op[lane] = o0; op[64 + lane] = o1; op[128 + lane] = o2; op[192 + lane] = o3;
}

// ---------------------------------------------------------------------------
extern "C" void kernel_launch(void* const* d_in, const int* in_sizes, int n_in,
                              void* d_out, int out_size, void* d_ws, size_t ws_size,
                              hipStream_t stream) {
  const float* x      = (const float*)d_in[0];
  const int*   ei     = (const int*)d_in[1];
  const float* W1     = (const float*)d_in[2];
  const float* att_s1 = (const float*)d_in[3];
  const float* att_d1 = (const float*)d_in[4];
  const float* b1     = (const float*)d_in[5];
  const float* W2     = (const float*)d_in[6];
  const float* att_s2 = (const float*)d_in[7];
  const float* att_d2 = (const float*)d_in[8];
  const float* b2     = (const float*)d_in[9];
  const float* Wm1    = (const float*)d_in[10];
  const float* bm1    = (const float*)d_in[11];
  const float* Wm2    = (const float*)d_in[12];
  const float* bm2    = (const float*)d_in[13];
  float* out = (float*)d_out;

  int n = in_sizes[0] / 128;   // 50000
  int E = in_sizes[1] / 2;     // 800000
  int Etot = E + n;

  // workspace carve-up (16B-aligned chunks)
  char* ws = (char*)d_ws;
  size_t off = 0;
  auto carve = [&](size_t bytes) {
    char* p = ws + off;
    off += (bytes + 255) & ~(size_t)255;
    return p;
  };
  float* hbuf = (float*)carve((size_t)n * HC * 4);   // h (both layers), later hm
  float* obuf = (float*)carve((size_t)n * HC * 4);   // out1 / out2
  float* as   = (float*)carve((size_t)n * HEADS * 4);
  float* ad   = (float*)carve((size_t)n * HEADS * 4);
  int*   deg  = (int*)carve((size_t)n * 4);
  int*   row  = (int*)carve((size_t)(n + 1) * 4);
  int*   cur  = (int*)carve((size_t)n * 4);
  int*   csr  = (int*)carve((size_t)Etot * 4);
  (void)ws_size;

  int nb256  = (n + 255) / 256;
  int rowsB  = (n + 63) / 64;

  // --- CSR build (dst-sorted adjacency, incl. self loops) ---
  deg_init<<<nb256, 256, 0, stream>>>(deg, n);
  deg_count<<<(E + 255) / 256, 256, 0, stream>>>(ei, E, deg);
  scan_rowstart<<<1, 1024, 0, stream>>>(deg, row, n);
  cursor_copy<<<nb256, 256, 0, stream>>>(row, cur, n);
  csr_fill<<<(Etot + 255) / 256, 256, 0, stream>>>(ei, E, n, cur, csr);

  // --- conv1 ---
  gemm_bias_act<<<dim3(HC / BN, rowsB), 256, 0, stream>>>(x, W1, nullptr, hbuf, n, HC, 128, 0);
  attn_coef<<<(n * HEADS + 255) / 256, 256, 0, stream>>>(hbuf, att_s1, att_d1, as, ad, n);
  gat_aggregate<<<(n + 3) / 4, 256, 0, stream>>>(hbuf, as, ad, row, csr, b1, obuf, n, 1);

  // --- conv2 ---
  gemm_bias_act<<<dim3(HC / BN, rowsB), 256, 0, stream>>>(obuf, W2, nullptr, hbuf, n, HC, HC, 0);
  attn_coef<<<(n * HEADS + 255) / 256, 256, 0, stream>>>(hbuf, att_s2, att_d2, as, ad, n);
  gat_aggregate<<<(n + 3) / 4, 256, 0, stream>>>(hbuf, as, ad, row, csr, b2, obuf, n, 1);

  // --- post_mp: Linear(256->64), Linear(64->121) + sigmoid ---
  gemm_bias_act<<<dim3(1, rowsB), 256, 0, stream>>>(obuf, Wm1, bm1, hbuf, n, 64, HC, 0);
  gemm_bias_act<<<dim3(2, rowsB), 256, 0, stream>>>(hbuf, Wm2, bm2, out, n, 121, 64, 2);
}

// Round 2
// 700.370 us; speedup vs baseline: 1.2039x; 1.2039x over previous
//
#include <hip/hip_runtime.h>
#include <hip/hip_bf16.h>
#include <float.h>

#define HEADS 4
#define HID 64
#define HC 256   // HEADS*HID
#define NEG_SLOPE 0.2f
#define EPS 1e-16f

typedef short bf16x8 __attribute__((ext_vector_type(8)));
typedef float f32x4 __attribute__((ext_vector_type(4)));
typedef unsigned short ushort8 __attribute__((ext_vector_type(8)));

// ---------------------------------------------------------------------------
// bf16 MFMA GEMM: C[MxN] = A[MxK] @ B[KxN] (+bias)(+act), B given TRANSPOSED
// as Bt[N][K]. A, Bt bf16; accumulate fp32; out fp32 (Cf) or bf16 (Cb).
// Tile 128x128, BK=32, 4 waves, each wave 64x64 via 4x4 MFMA 16x16x32 tiles.
// act: 0=none, 1=relu, 2=sigmoid. K multiple of 32. M,N arbitrary (clamped
// staging + guarded stores).
// ---------------------------------------------------------------------------
#define PK 40  // padded LDS row stride in bf16 elems (32 + 8 -> 80B, 16B-aligned)

__global__ void __launch_bounds__(256) mfma_gemm(
    const __hip_bfloat16* __restrict__ A, const __hip_bfloat16* __restrict__ Bt,
    const float* __restrict__ bias, float* __restrict__ Cf,
    __hip_bfloat16* __restrict__ Cb, int M, int N, int K, int act) {
  __shared__ unsigned short As[128 * PK];
  __shared__ unsigned short Bs[128 * PK];
  int tid = threadIdx.x;
  int lane = tid & 63, w = tid >> 6;
  int wm = w & 1, wn = w >> 1;
  int col16 = lane & 15, quad = lane >> 4;
  int row0 = blockIdx.y * 128, col0 = blockIdx.x * 128;
  const unsigned short* Ag = (const unsigned short*)A;
  const unsigned short* Bg = (const unsigned short*)Bt;

  f32x4 acc[4][4] = {};

  for (int k0 = 0; k0 < K; k0 += 32) {
    // stage A tile [128 rows x 32 k] : 512 chunks of 8 bf16 (16B)
#pragma unroll
    for (int c = tid; c < 512; c += 256) {
      int r = c >> 2, ko = (c & 3) << 3;
      int gr = row0 + r;
      if (gr >= M) gr = M - 1;
      ushort8 v = *(const ushort8*)(Ag + (size_t)gr * K + k0 + ko);
      *(ushort8*)(&As[r * PK + ko]) = v;
    }
    // stage Bt tile [128 cols x 32 k]
#pragma unroll
    for (int c = tid; c < 512; c += 256) {
      int r = c >> 2, ko = (c & 3) << 3;
      int gc = col0 + r;
      if (gc >= N) gc = N - 1;
      ushort8 v = *(const ushort8*)(Bg + (size_t)gc * K + k0 + ko);
      *(ushort8*)(&Bs[r * PK + ko]) = v;
    }
    __syncthreads();
    bf16x8 a[4], b[4];
#pragma unroll
    for (int i = 0; i < 4; i++)
      a[i] = *(const bf16x8*)(&As[(wm * 64 + i * 16 + col16) * PK + quad * 8]);
#pragma unroll
    for (int j = 0; j < 4; j++)
      b[j] = *(const bf16x8*)(&Bs[(wn * 64 + j * 16 + col16) * PK + quad * 8]);
#pragma unroll
    for (int i = 0; i < 4; i++)
#pragma unroll
      for (int j = 0; j < 4; j++)
        acc[i][j] = __builtin_amdgcn_mfma_f32_16x16x32_bf16(a[i], b[j], acc[i][j], 0, 0, 0);
    __syncthreads();
  }

  // epilogue: C/D layout col=lane&15, row=quad*4+reg
#pragma unroll
  for (int i = 0; i < 4; i++) {
#pragma unroll
    for (int j = 0; j < 4; j++) {
      int gc = col0 + wn * 64 + j * 16 + col16;
      if (gc >= N) continue;
      int grb = row0 + wm * 64 + i * 16 + quad * 4;
      float bv = bias ? bias[gc] : 0.f;
#pragma unroll
      for (int r = 0; r < 4; r++) {
        int gr = grb + r;
        if (gr >= M) continue;
        float v = acc[i][j][r] + bv;
        if (act == 1) v = fmaxf(v, 0.f);
        else if (act == 2) v = 1.f / (1.f + __expf(-v));
        if (Cb) Cb[(size_t)gr * N + gc] = __float2bfloat16(v);
        else Cf[(size_t)gr * N + gc] = v;
      }
    }
  }
}

// ---------------------------------------------------------------------------
// casts
// ---------------------------------------------------------------------------
__global__ void cast_bf16(const float* __restrict__ src, __hip_bfloat16* __restrict__ dst, int count) {
  int i = blockIdx.x * 256 + threadIdx.x;
  if (i < count) dst[i] = __float2bfloat16(src[i]);
}

// Bt[n][k] = B[k][n], bf16
__global__ void transpose_cast(const float* __restrict__ B, __hip_bfloat16* __restrict__ Bt,
                               int K, int N) {
  int i = blockIdx.x * 256 + threadIdx.x;
  if (i >= N * K) return;
  int nn = i / K, kk = i - nn * K;
  Bt[i] = __float2bfloat16(B[(size_t)kk * N + nn]);
}

// ---------------------------------------------------------------------------
// Attention coefficients (fp32 h): a_s[n,h]=<h[n,h,:],att_src[h,:]>, same a_d
// ---------------------------------------------------------------------------
__global__ void attn_coef(const float* __restrict__ h,
                          const float* __restrict__ att_s,
                          const float* __restrict__ att_d,
                          float* __restrict__ a_s, float* __restrict__ a_d,
                          int n) {
  int idx = blockIdx.x * 256 + threadIdx.x;
  if (idx >= n * HEADS) return;
  int node = idx >> 2, hd = idx & 3;
  const float* hp = h + (size_t)node * HC + hd * HID;
  const float* ws = att_s + hd * HID;
  const float* wd = att_d + hd * HID;
  float ss = 0.f, sd = 0.f;
#pragma unroll 8
  for (int c = 0; c < HID; ++c) {
    float v = hp[c];
    ss += v * ws[c];
    sd += v * wd[c];
  }
  a_s[idx] = ss;
  a_d[idx] = sd;
}

// ---------------------------------------------------------------------------
// CSR build
// ---------------------------------------------------------------------------
__global__ void deg_init(int* __restrict__ deg, int n) {
  int i = blockIdx.x * 256 + threadIdx.x;
  if (i < n) deg[i] = 1;  // self loop
}

__global__ void deg_count(const int* __restrict__ ei, int E, int* __restrict__ deg) {
  int i = blockIdx.x * 256 + threadIdx.x;
  if (i < E) atomicAdd(&deg[ei[E + i]], 1);  // row 1 = dst
}

__global__ void __launch_bounds__(1024) scan_rowstart(
    const int* __restrict__ deg, int* __restrict__ row_start, int n) {
  __shared__ int wave_tot[16];
  __shared__ int carry_s;
  int tid = threadIdx.x;
  int lane = tid & 63, wid = tid >> 6;
  if (tid == 0) { carry_s = 0; row_start[0] = 0; }
  __syncthreads();
  for (int base = 0; base < n; base += 1024) {
    int i = base + tid;
    int v = (i < n) ? deg[i] : 0;
    int s = v;
#pragma unroll
    for (int off = 1; off < 64; off <<= 1) {
      int t = __shfl_up(s, off);
      if (lane >= off) s += t;
    }
    if (lane == 63) wave_tot[wid] = s;
    __syncthreads();
    if (wid == 0) {
      int wv = (lane < 16) ? wave_tot[lane] : 0;
      int ws = wv;
#pragma unroll
      for (int off = 1; off < 16; off <<= 1) {
        int t = __shfl_up(ws, off);
        if (lane >= off) ws += t;
      }
      if (lane < 16) wave_tot[lane] = ws;
    }
    __syncthreads();
    int offset = carry_s + (wid > 0 ? wave_tot[wid - 1] : 0);
    if (i < n) row_start[i + 1] = offset + s;
    __syncthreads();
    if (tid == 0) carry_s += wave_tot[15];
    __syncthreads();
  }
}

__global__ void cursor_copy(const int* __restrict__ row_start, int* __restrict__ cur, int n) {
  int i = blockIdx.x * 256 + threadIdx.x;
  if (i < n) cur[i] = row_start[i];
}

__global__ void csr_fill(const int* __restrict__ ei, int E, int n,
                         int* __restrict__ cur, int* __restrict__ csr_src) {
  int i = blockIdx.x * 256 + threadIdx.x;
  int Etot = E + n;
  if (i >= Etot) return;
  int s, d;
  if (i < E) { s = ei[i]; d = ei[E + i]; }
  else { s = d = i - E; }
  int pos = atomicAdd(&cur[d], 1);
  csr_src[pos] = s;
}

// ---------------------------------------------------------------------------
// GAT aggregation: one wave per destination node, online softmax.
// Lane t holds channel t of each of the 4 heads. Output bf16 (+bias, relu).
// ---------------------------------------------------------------------------
__device__ __forceinline__ void online_upd(float e, float hv, float& m, float& l, float& c) {
  if (e > m) {
    float sc = __expf(m - e);
    l *= sc; c *= sc; m = e;
  }
  float p = __expf(e - m);
  l += p; c += p * hv;
}

__global__ void __launch_bounds__(256) gat_aggregate(
    const float* __restrict__ h, const float* __restrict__ a_src,
    const float* __restrict__ a_dst, const int* __restrict__ row_start,
    const int* __restrict__ csr_src, const float* __restrict__ bias,
    __hip_bfloat16* __restrict__ out, int n) {
  int wid = threadIdx.x >> 6;
  int lane = threadIdx.x & 63;
  int node = (blockIdx.x << 2) + wid;
  if (node >= n) return;
  float ad0 = a_dst[node * 4 + 0], ad1 = a_dst[node * 4 + 1];
  float ad2 = a_dst[node * 4 + 2], ad3 = a_dst[node * 4 + 3];
  float m0 = -FLT_MAX, m1 = -FLT_MAX, m2 = -FLT_MAX, m3 = -FLT_MAX;
  float l0 = 0.f, l1 = 0.f, l2 = 0.f, l3 = 0.f;
  float c0 = 0.f, c1 = 0.f, c2 = 0.f, c3 = 0.f;
  int beg = row_start[node], end = row_start[node + 1];
  for (int e = beg; e < end; ++e) {
    int s = csr_src[e];
    const float* hp = h + (size_t)s * HC;
    float as0 = a_src[s * 4 + 0], as1 = a_src[s * 4 + 1];
    float as2 = a_src[s * 4 + 2], as3 = a_src[s * 4 + 3];
    float h0 = hp[lane], h1 = hp[64 + lane], h2 = hp[128 + lane], h3 = hp[192 + lane];
    float e0 = as0 + ad0; e0 = (e0 > 0.f) ? e0 : NEG_SLOPE * e0;
    float e1 = as1 + ad1; e1 = (e1 > 0.f) ? e1 : NEG_SLOPE * e1;
    float e2 = as2 + ad2; e2 = (e2 > 0.f) ? e2 : NEG_SLOPE * e2;
    float e3 = as3 + ad3; e3 = (e3 > 0.f) ? e3 : NEG_SLOPE * e3;
    online_upd(e0, h0, m0, l0, c0);
    online_upd(e1, h1, m1, l1, c1);
    online_upd(e2, h2, m2, l2, c2);
    online_upd(e3, h3, m3, l3, c3);
  }
  float o0 = fmaxf(c0 / (l0 + EPS) + bias[lane], 0.f);
  float o1 = fmaxf(c1 / (l1 + EPS) + bias[64 + lane], 0.f);
  float o2 = fmaxf(c2 / (l2 + EPS) + bias[128 + lane], 0.f);
  float o3 = fmaxf(c3 / (l3 + EPS) + bias[192 + lane], 0.f);
  __hip_bfloat16* op = out + (size_t)node * HC;
  op[lane] = __float2bfloat16(o0);
  op[64 + lane] = __float2bfloat16(o1);
  op[128 + lane] = __float2bfloat16(o2);
  op[192 + lane] = __float2bfloat16(o3);
}

// ---------------------------------------------------------------------------
extern "C" void kernel_launch(void* const* d_in, const int* in_sizes, int n_in,
                              void* d_out, int out_size, void* d_ws, size_t ws_size,
                              hipStream_t stream) {
  const float* x      = (const float*)d_in[0];
  const int*   ei     = (const int*)d_in[1];
  const float* W1     = (const float*)d_in[2];
  const float* att_s1 = (const float*)d_in[3];
  const float* att_d1 = (const float*)d_in[4];
  const float* b1     = (const float*)d_in[5];
  const float* W2     = (const float*)d_in[6];
  const float* att_s2 = (const float*)d_in[7];
  const float* att_d2 = (const float*)d_in[8];
  const float* b2     = (const float*)d_in[9];
  const float* Wm1    = (const float*)d_in[10];
  const float* bm1    = (const float*)d_in[11];
  const float* Wm2    = (const float*)d_in[12];
  const float* bm2    = (const float*)d_in[13];
  float* out = (float*)d_out;

  int n = in_sizes[0] / 128;   // 50000
  int E = in_sizes[1] / 2;     // 800000
  int Etot = E + n;

  char* ws = (char*)d_ws;
  size_t off = 0;
  auto carve = [&](size_t bytes) {
    char* p = ws + off;
    off += (bytes + 255) & ~(size_t)255;
    return p;
  };
  float*          h    = (float*)carve((size_t)n * HC * 4);           // GEMM1/GEMM2 out (fp32)
  __hip_bfloat16* aggb = (__hip_bfloat16*)carve((size_t)n * HC * 2);  // agg out (bf16)
  __hip_bfloat16* xb   = (__hip_bfloat16*)carve((size_t)n * 128 * 2);
  __hip_bfloat16* pm1b = (__hip_bfloat16*)carve((size_t)n * HID * 2);
  __hip_bfloat16* W1t  = (__hip_bfloat16*)carve((size_t)128 * HC * 2);
  __hip_bfloat16* W2t  = (__hip_bfloat16*)carve((size_t)HC * HC * 2);
  __hip_bfloat16* Wm1t = (__hip_bfloat16*)carve((size_t)HC * HID * 2);
  __hip_bfloat16* Wm2t = (__hip_bfloat16*)carve((size_t)HID * 121 * 2);
  float* as  = (float*)carve((size_t)n * HEADS * 4);
  float* ad  = (float*)carve((size_t)n * HEADS * 4);
  int*   deg = (int*)carve((size_t)n * 4);
  int*   row = (int*)carve((size_t)(n + 1) * 4);
  int*   cur = (int*)carve((size_t)n * 4);
  int*   csr = (int*)carve((size_t)Etot * 4);
  (void)ws_size;

  int nb256 = (n + 255) / 256;
  int rows128 = (n + 127) / 128;

  // --- input casts ---
  cast_bf16<<<(n * 128 + 255) / 256, 256, 0, stream>>>(x, xb, n * 128);
  transpose_cast<<<(HC * 128 + 255) / 256, 256, 0, stream>>>(W1, W1t, 128, HC);
  transpose_cast<<<(HC * HC + 255) / 256, 256, 0, stream>>>(W2, W2t, HC, HC);
  transpose_cast<<<(HID * HC + 255) / 256, 256, 0, stream>>>(Wm1, Wm1t, HC, HID);
  transpose_cast<<<(121 * HID + 255) / 256, 256, 0, stream>>>(Wm2, Wm2t, HID, 121);

  // --- CSR build ---
  deg_init<<<nb256, 256, 0, stream>>>(deg, n);
  deg_count<<<(E + 255) / 256, 256, 0, stream>>>(ei, E, deg);
  scan_rowstart<<<1, 1024, 0, stream>>>(deg, row, n);
  cursor_copy<<<nb256, 256, 0, stream>>>(row, cur, n);
  csr_fill<<<(Etot + 255) / 256, 256, 0, stream>>>(ei, E, n, cur, csr);

  // --- conv1 ---
  mfma_gemm<<<dim3(2, rows128), 256, 0, stream>>>(xb, W1t, nullptr, h, nullptr, n, HC, 128, 0);
  attn_coef<<<(n * HEADS + 255) / 256, 256, 0, stream>>>(h, att_s1, att_d1, as, ad, n);
  gat_aggregate<<<(n + 3) / 4, 256, 0, stream>>>(h, as, ad, row, csr, b1, aggb, n);

  // --- conv2 ---
  mfma_gemm<<<dim3(2, rows128), 256, 0, stream>>>(aggb, W2t, nullptr, h, nullptr, n, HC, HC, 0);
  attn_coef<<<(n * HEADS + 255) / 256, 256, 0, stream>>>(h, att_s2, att_d2, as, ad, n);
  gat_aggregate<<<(n + 3) / 4, 256, 0, stream>>>(h, as, ad, row, csr, b2, aggb, n);

  // --- post_mp ---
  mfma_gemm<<<dim3(1, rows128), 256, 0, stream>>>(aggb, Wm1t, bm1, nullptr, pm1b, n, HID, HC, 0);
  mfma_gemm<<<dim3(1, rows128), 256, 0, stream>>>(pm1b, Wm2t, bm2, out, nullptr, n, 121, HID, 2);
}

// Round 3
// 591.073 us; speedup vs baseline: 1.4265x; 1.1849x over previous
//
#include <hip/hip_runtime.h>
#include <hip/hip_bf16.h>
#include <float.h>

#define HEADS 4
#define HID 64
#define HC 256   // HEADS*HID
#define NEG_SLOPE 0.2f
#define EPS 1e-16f

typedef short bf16x8 __attribute__((ext_vector_type(8)));
typedef float f32x4 __attribute__((ext_vector_type(4)));
typedef unsigned short ushort8 __attribute__((ext_vector_type(8)));

__device__ __forceinline__ float bflo(unsigned u) { return __uint_as_float(u << 16); }
__device__ __forceinline__ float bfhi(unsigned u) { return __uint_as_float(u & 0xffff0000u); }
__device__ __forceinline__ unsigned packbf2(float a, float b) {
  __hip_bfloat16 ha = __float2bfloat16(a), hb = __float2bfloat16(b);
  unsigned short ua = *reinterpret_cast<unsigned short*>(&ha);
  unsigned short ub = *reinterpret_cast<unsigned short*>(&hb);
  return (unsigned)ua | ((unsigned)ub << 16);
}

// ---------------------------------------------------------------------------
// bf16 MFMA GEMM: C[MxN] = A[MxK] @ Bt^T (+bias)(+act). Bt is [N][K] bf16.
// Tile 128x128, BK=32, 4 waves. Out fp32 (Cf) or bf16 (Cb).
// act: 0=none, 2=sigmoid. K multiple of 32.
// ---------------------------------------------------------------------------
#define PK 40  // padded LDS row stride (bf16 elems)

__global__ void __launch_bounds__(256) mfma_gemm(
    const __hip_bfloat16* __restrict__ A, const __hip_bfloat16* __restrict__ Bt,
    const float* __restrict__ bias, float* __restrict__ Cf,
    __hip_bfloat16* __restrict__ Cb, int M, int N, int K, int act) {
  __shared__ unsigned short As[128 * PK];
  __shared__ unsigned short Bs[128 * PK];
  int tid = threadIdx.x;
  int lane = tid & 63, w = tid >> 6;
  int wm = w & 1, wn = w >> 1;
  int col16 = lane & 15, quad = lane >> 4;
  int row0 = blockIdx.y * 128, col0 = blockIdx.x * 128;
  const unsigned short* Ag = (const unsigned short*)A;
  const unsigned short* Bg = (const unsigned short*)Bt;

  f32x4 acc[4][4] = {};

  for (int k0 = 0; k0 < K; k0 += 32) {
#pragma unroll
    for (int c = tid; c < 512; c += 256) {
      int r = c >> 2, ko = (c & 3) << 3;
      int gr = row0 + r;
      if (gr >= M) gr = M - 1;
      ushort8 v = *(const ushort8*)(Ag + (size_t)gr * K + k0 + ko);
      *(ushort8*)(&As[r * PK + ko]) = v;
    }
#pragma unroll
    for (int c = tid; c < 512; c += 256) {
      int r = c >> 2, ko = (c & 3) << 3;
      int gc = col0 + r;
      if (gc >= N) gc = N - 1;
      ushort8 v = *(const ushort8*)(Bg + (size_t)gc * K + k0 + ko);
      *(ushort8*)(&Bs[r * PK + ko]) = v;
    }
    __syncthreads();
    bf16x8 a[4], b[4];
#pragma unroll
    for (int i = 0; i < 4; i++)
      a[i] = *(const bf16x8*)(&As[(wm * 64 + i * 16 + col16) * PK + quad * 8]);
#pragma unroll
    for (int j = 0; j < 4; j++)
      b[j] = *(const bf16x8*)(&Bs[(wn * 64 + j * 16 + col16) * PK + quad * 8]);
#pragma unroll
    for (int i = 0; i < 4; i++)
#pragma unroll
      for (int j = 0; j < 4; j++)
        acc[i][j] = __builtin_amdgcn_mfma_f32_16x16x32_bf16(a[i], b[j], acc[i][j], 0, 0, 0);
    __syncthreads();
  }

#pragma unroll
  for (int i = 0; i < 4; i++) {
#pragma unroll
    for (int j = 0; j < 4; j++) {
      int gc = col0 + wn * 64 + j * 16 + col16;
      if (gc >= N) continue;
      int grb = row0 + wm * 64 + i * 16 + quad * 4;
      float bv = bias ? bias[gc] : 0.f;
#pragma unroll
      for (int r = 0; r < 4; r++) {
        int gr = grb + r;
        if (gr >= M) continue;
        float v = acc[i][j][r] + bv;
        if (act == 2) v = 1.f / (1.f + __expf(-v));
        if (Cb) Cb[(size_t)gr * N + gc] = __float2bfloat16(v);
        else Cf[(size_t)gr * N + gc] = v;
      }
    }
  }
}

// ---------------------------------------------------------------------------
// casts
// ---------------------------------------------------------------------------
__global__ void cast_bf16(const float* __restrict__ src, __hip_bfloat16* __restrict__ dst, int count) {
  int i = blockIdx.x * 256 + threadIdx.x;
  if (i < count) dst[i] = __float2bfloat16(src[i]);
}

__global__ void transpose_cast(const float* __restrict__ B, __hip_bfloat16* __restrict__ Bt,
                               int K, int N) {
  int i = blockIdx.x * 256 + threadIdx.x;
  if (i >= N * K) return;
  int nn = i / K, kk = i - nn * K;
  Bt[i] = __float2bfloat16(B[(size_t)kk * N + nn]);
}

// ---------------------------------------------------------------------------
// Attention coefficients from bf16 h: a_s[n,h]=<h[n,h,:],att_src[h,:]>
// One thread per (node, head); uint4 (8 bf16) vector loads.
// ---------------------------------------------------------------------------
__global__ void attn_coef(const __hip_bfloat16* __restrict__ h,
                          const float* __restrict__ att_s,
                          const float* __restrict__ att_d,
                          float* __restrict__ a_s, float* __restrict__ a_d,
                          int n) {
  int idx = blockIdx.x * 256 + threadIdx.x;
  if (idx >= n * HEADS) return;
  int node = idx >> 2, hd = idx & 3;
  const uint4* hp = (const uint4*)((const unsigned short*)h + (size_t)node * HC + hd * HID);
  const float* wsv = att_s + hd * HID;
  const float* wdv = att_d + hd * HID;
  float ss = 0.f, sd = 0.f;
#pragma unroll
  for (int i = 0; i < 8; i++) {
    uint4 u = hp[i];
    float f[8] = {bflo(u.x), bfhi(u.x), bflo(u.y), bfhi(u.y),
                  bflo(u.z), bfhi(u.z), bflo(u.w), bfhi(u.w)};
#pragma unroll
    for (int j = 0; j < 8; j++) {
      int c = i * 8 + j;
      ss += f[j] * wsv[c];
      sd += f[j] * wdv[c];
    }
  }
  a_s[idx] = ss;
  a_d[idx] = sd;
}

// ---------------------------------------------------------------------------
// CSR build: degree histogram, two-level parallel scan, scatter fill.
// ---------------------------------------------------------------------------
__global__ void deg_init(int* __restrict__ deg, int n) {
  int i = blockIdx.x * 256 + threadIdx.x;
  if (i < n) deg[i] = 1;  // self loop
}

__global__ void deg_count(const int* __restrict__ ei, int E, int* __restrict__ deg) {
  int i = blockIdx.x * 256 + threadIdx.x;
  if (i < E) atomicAdd(&deg[ei[E + i]], 1);
}

// per-block inclusive scan; row_start[i+1] = local inclusive, bsum[b] = block total
__global__ void __launch_bounds__(256) scan_block(const int* __restrict__ deg,
                                                  int* __restrict__ row_start,
                                                  int* __restrict__ bsum, int n) {
  __shared__ int wt[4];
  int tid = threadIdx.x, lane = tid & 63, w = tid >> 6;
  int i = blockIdx.x * 256 + tid;
  int v = (i < n) ? deg[i] : 0;
  int s = v;
#pragma unroll
  for (int off = 1; off < 64; off <<= 1) {
    int t = __shfl_up(s, off);
    if (lane >= off) s += t;
  }
  if (lane == 63) wt[w] = s;
  __syncthreads();
  int add = 0;
  if (w > 0) add += wt[0];
  if (w > 1) add += wt[1];
  if (w > 2) add += wt[2];
  if (i < n) row_start[i + 1] = s + add;
  if (tid == 0) bsum[blockIdx.x] = wt[0] + wt[1] + wt[2] + wt[3];
}

// exclusive scan of block sums (nb <= 256), in place
__global__ void __launch_bounds__(256) scan_partials(int* __restrict__ bsum, int nb) {
  __shared__ int wt[4];
  int tid = threadIdx.x, lane = tid & 63, w = tid >> 6;
  int v = (tid < nb) ? bsum[tid] : 0;
  int s = v;
#pragma unroll
  for (int off = 1; off < 64; off <<= 1) {
    int t = __shfl_up(s, off);
    if (lane >= off) s += t;
  }
  if (lane == 63) wt[w] = s;
  __syncthreads();
  int add = 0;
  if (w > 0) add += wt[0];
  if (w > 1) add += wt[1];
  if (w > 2) add += wt[2];
  if (tid < nb) bsum[tid] = s + add - v;  // exclusive
}

// row_start[i+1] += bsum_ex[block]; cur[i] = row_start[i] (= incl - deg)
__global__ void finalize_row(int* __restrict__ row_start, const int* __restrict__ bsum_ex,
                             const int* __restrict__ deg, int* __restrict__ cur, int n) {
  int i = blockIdx.x * 256 + threadIdx.x;
  if (i == 0) row_start[0] = 0;
  if (i < n) {
    int v = row_start[i + 1] + bsum_ex[blockIdx.x];
    row_start[i + 1] = v;
    cur[i] = v - deg[i];
  }
}

__global__ void csr_fill(const int* __restrict__ ei, int E, int n,
                         int* __restrict__ cur, int* __restrict__ csr_src) {
  int i = blockIdx.x * 256 + threadIdx.x;
  int Etot = E + n;
  if (i >= Etot) return;
  int s, d;
  if (i < E) { s = ei[i]; d = ei[E + i]; }
  else { s = d = i - E; }
  int pos = atomicAdd(&cur[d], 1);
  csr_src[pos] = s;
}

// ---------------------------------------------------------------------------
// GAT aggregation, two-pass softmax, bf16 h gather.
// One wave per dst node. Phase 1: lanes stride edges, per-head max, shuffle
// reduce. Phase 2: lane t holds channel pair (2t,2t+1) [load A: heads 0/1]
// and (128+2t,129+2t+1) [load B: heads 2/3]; 2 exps/lane/edge, no branches.
// Output bf16 with bias+relu fused.
// ---------------------------------------------------------------------------
__global__ void __launch_bounds__(256) gat_aggregate(
    const __hip_bfloat16* __restrict__ hb, const float* __restrict__ a_src,
    const float* __restrict__ a_dst, const int* __restrict__ row_start,
    const int* __restrict__ csr_src, const float* __restrict__ bias,
    __hip_bfloat16* __restrict__ out, int n) {
  int wid = threadIdx.x >> 6;
  int lane = threadIdx.x & 63;
  int node = (blockIdx.x << 2) + wid;
  if (node >= n) return;
  float4 adv = *(const float4*)(a_dst + (size_t)node * 4);
  int beg = row_start[node], end = row_start[node + 1];

  // ---- phase 1: per-head max over incoming edges ----
  float m0 = -FLT_MAX, m1 = -FLT_MAX, m2 = -FLT_MAX, m3 = -FLT_MAX;
  for (int e = beg + lane; e < end; e += 64) {
    int s = csr_src[e];
    float4 as = *(const float4*)(a_src + (size_t)s * 4);
    float v0 = as.x + adv.x; v0 = fmaxf(v0, NEG_SLOPE * v0);
    float v1 = as.y + adv.y; v1 = fmaxf(v1, NEG_SLOPE * v1);
    float v2 = as.z + adv.z; v2 = fmaxf(v2, NEG_SLOPE * v2);
    float v3 = as.w + adv.w; v3 = fmaxf(v3, NEG_SLOPE * v3);
    m0 = fmaxf(m0, v0); m1 = fmaxf(m1, v1);
    m2 = fmaxf(m2, v2); m3 = fmaxf(m3, v3);
  }
#pragma unroll
  for (int off = 32; off; off >>= 1) {
    m0 = fmaxf(m0, __shfl_xor(m0, off));
    m1 = fmaxf(m1, __shfl_xor(m1, off));
    m2 = fmaxf(m2, __shfl_xor(m2, off));
    m3 = fmaxf(m3, __shfl_xor(m3, off));
  }

  // ---- phase 2: weighted sum ----
  bool lo = lane < 32;
  float mA = lo ? m0 : m1, mB = lo ? m2 : m3;
  const unsigned* hw = (const unsigned*)hb;
  float lA = 0.f, lB = 0.f;
  float cA0 = 0.f, cA1 = 0.f, cB0 = 0.f, cB1 = 0.f;
  for (int e = beg; e < end; ++e) {
    int s = csr_src[e];
    float4 as = *(const float4*)(a_src + (size_t)s * 4);
    unsigned dA = hw[(size_t)s * 128 + lane];
    unsigned dB = hw[(size_t)s * 128 + 64 + lane];
    float v0 = as.x + adv.x; v0 = fmaxf(v0, NEG_SLOPE * v0);
    float v1 = as.y + adv.y; v1 = fmaxf(v1, NEG_SLOPE * v1);
    float v2 = as.z + adv.z; v2 = fmaxf(v2, NEG_SLOPE * v2);
    float v3 = as.w + adv.w; v3 = fmaxf(v3, NEG_SLOPE * v3);
    float eA = lo ? v0 : v1, eB = lo ? v2 : v3;
    float pA = __expf(eA - mA);
    float pB = __expf(eB - mB);
    lA += pA; lB += pB;
    cA0 += pA * bflo(dA); cA1 += pA * bfhi(dA);
    cB0 += pB * bflo(dB); cB1 += pB * bfhi(dB);
  }
  float2 bA = *(const float2*)(bias + 2 * lane);
  float2 bB = *(const float2*)(bias + 128 + 2 * lane);
  float rA = 1.f / (lA + EPS), rB = 1.f / (lB + EPS);
  float oA0 = fmaxf(cA0 * rA + bA.x, 0.f);
  float oA1 = fmaxf(cA1 * rA + bA.y, 0.f);
  float oB0 = fmaxf(cB0 * rB + bB.x, 0.f);
  float oB1 = fmaxf(cB1 * rB + bB.y, 0.f);
  unsigned* ow = (unsigned*)out;
  ow[(size_t)node * 128 + lane] = packbf2(oA0, oA1);
  ow[(size_t)node * 128 + 64 + lane] = packbf2(oB0, oB1);
}

// ---------------------------------------------------------------------------
extern "C" void kernel_launch(void* const* d_in, const int* in_sizes, int n_in,
                              void* d_out, int out_size, void* d_ws, size_t ws_size,
                              hipStream_t stream) {
  const float* x      = (const float*)d_in[0];
  const int*   ei     = (const int*)d_in[1];
  const float* W1     = (const float*)d_in[2];
  const float* att_s1 = (const float*)d_in[3];
  const float* att_d1 = (const float*)d_in[4];
  const float* b1     = (const float*)d_in[5];
  const float* W2     = (const float*)d_in[6];
  const float* att_s2 = (const float*)d_in[7];
  const float* att_d2 = (const float*)d_in[8];
  const float* b2     = (const float*)d_in[9];
  const float* Wm1    = (const float*)d_in[10];
  const float* bm1    = (const float*)d_in[11];
  const float* Wm2    = (const float*)d_in[12];
  const float* bm2    = (const float*)d_in[13];
  float* out = (float*)d_out;

  int n = in_sizes[0] / 128;   // 50000
  int E = in_sizes[1] / 2;     // 800000
  int Etot = E + n;

  char* ws = (char*)d_ws;
  size_t off = 0;
  auto carve = [&](size_t bytes) {
    char* p = ws + off;
    off += (bytes + 255) & ~(size_t)255;
    return p;
  };
  __hip_bfloat16* hb   = (__hip_bfloat16*)carve((size_t)n * HC * 2);  // GEMM out (bf16)
  __hip_bfloat16* aggb = (__hip_bfloat16*)carve((size_t)n * HC * 2);  // agg out (bf16)
  __hip_bfloat16* xb   = (__hip_bfloat16*)carve((size_t)n * 128 * 2);
  __hip_bfloat16* pm1b = (__hip_bfloat16*)carve((size_t)n * HID * 2);
  __hip_bfloat16* W1t  = (__hip_bfloat16*)carve((size_t)128 * HC * 2);
  __hip_bfloat16* W2t  = (__hip_bfloat16*)carve((size_t)HC * HC * 2);
  __hip_bfloat16* Wm1t = (__hip_bfloat16*)carve((size_t)HC * HID * 2);
  __hip_bfloat16* Wm2t = (__hip_bfloat16*)carve((size_t)HID * 121 * 2);
  float* as   = (float*)carve((size_t)n * HEADS * 4);
  float* ad   = (float*)carve((size_t)n * HEADS * 4);
  int*   deg  = (int*)carve((size_t)n * 4);
  int*   row  = (int*)carve((size_t)(n + 1) * 4);
  int*   cur  = (int*)carve((size_t)n * 4);
  int*   csr  = (int*)carve((size_t)Etot * 4);
  int*   bsum = (int*)carve((size_t)1024 * 4);
  (void)ws_size;

  int nb256 = (n + 255) / 256;
  int rows128 = (n + 127) / 128;

  // --- input casts ---
  cast_bf16<<<(n * 128 + 255) / 256, 256, 0, stream>>>(x, xb, n * 128);
  transpose_cast<<<(HC * 128 + 255) / 256, 256, 0, stream>>>(W1, W1t, 128, HC);
  transpose_cast<<<(HC * HC + 255) / 256, 256, 0, stream>>>(W2, W2t, HC, HC);
  transpose_cast<<<(HID * HC + 255) / 256, 256, 0, stream>>>(Wm1, Wm1t, HC, HID);
  transpose_cast<<<(121 * HID + 255) / 256, 256, 0, stream>>>(Wm2, Wm2t, HID, 121);

  // --- CSR build ---
  deg_init<<<nb256, 256, 0, stream>>>(deg, n);
  deg_count<<<(E + 255) / 256, 256, 0, stream>>>(ei, E, deg);
  scan_block<<<nb256, 256, 0, stream>>>(deg, row, bsum, n);
  scan_partials<<<1, 256, 0, stream>>>(bsum, nb256);
  finalize_row<<<nb256, 256, 0, stream>>>(row, bsum, deg, cur, n);
  csr_fill<<<(Etot + 255) / 256, 256, 0, stream>>>(ei, E, n, cur, csr);

  // --- conv1 ---
  mfma_gemm<<<dim3(2, rows128), 256, 0, stream>>>(xb, W1t, nullptr, nullptr, hb, n, HC, 128, 0);
  attn_coef<<<(n * HEADS + 255) / 256, 256, 0, stream>>>(hb, att_s1, att_d1, as, ad, n);
  gat_aggregate<<<(n + 3) / 4, 256, 0, stream>>>(hb, as, ad, row, csr, b1, aggb, n);

  // --- conv2 ---
  mfma_gemm<<<dim3(2, rows128), 256, 0, stream>>>(aggb, W2t, nullptr, nullptr, hb, n, HC, HC, 0);
  attn_coef<<<(n * HEADS + 255) / 256, 256, 0, stream>>>(hb, att_s2, att_d2, as, ad, n);
  gat_aggregate<<<(n + 3) / 4, 256, 0, stream>>>(hb, as, ad, row, csr, b2, aggb, n);

  // --- post_mp ---
  mfma_gemm<<<dim3(1, rows128), 256, 0, stream>>>(aggb, Wm1t, bm1, nullptr, pm1b, n, HID, HC, 0);
  mfma_gemm<<<dim3(1, rows128), 256, 0, stream>>>(pm1b, Wm2t, bm2, out, nullptr, n, 121, HID, 2);
}

// Round 4
// 484.319 us; speedup vs baseline: 1.7409x; 1.2204x over previous
//
#include <hip/hip_runtime.h>
#include <hip/hip_bf16.h>
#include <float.h>

#define HEADS 4
#define HID 64
#define HC 256   // HEADS*HID
#define NEG_SLOPE 0.2f
#define EPS 1e-16f

typedef short bf16x8 __attribute__((ext_vector_type(8)));
typedef float f32x4 __attribute__((ext_vector_type(4)));
typedef unsigned short ushort8 __attribute__((ext_vector_type(8)));

__device__ __forceinline__ float bflo(unsigned u) { return __uint_as_float(u << 16); }
__device__ __forceinline__ float bfhi(unsigned u) { return __uint_as_float(u & 0xffff0000u); }
__device__ __forceinline__ unsigned packbf2(float a, float b) {
  __hip_bfloat16 ha = __float2bfloat16(a), hb = __float2bfloat16(b);
  unsigned short ua = *reinterpret_cast<unsigned short*>(&ha);
  unsigned short ub = *reinterpret_cast<unsigned short*>(&hb);
  return (unsigned)ua | ((unsigned)ub << 16);
}

// ---------------------------------------------------------------------------
// bf16 MFMA GEMM: C[MxN] = A[MxK] @ Bt^T (+bias)(+act). Bt is [N][K] bf16.
// Tile 128x128, BK=32, 4 waves. Out fp32 (Cf) or bf16 (Cb).
// act: 0=none, 2=sigmoid. K multiple of 32.
// ---------------------------------------------------------------------------
#define PK 40  // padded LDS row stride (bf16 elems)

__global__ void __launch_bounds__(256) mfma_gemm(
    const __hip_bfloat16* __restrict__ A, const __hip_bfloat16* __restrict__ Bt,
    const float* __restrict__ bias, float* __restrict__ Cf,
    __hip_bfloat16* __restrict__ Cb, int M, int N, int K, int act) {
  __shared__ unsigned short As[128 * PK];
  __shared__ unsigned short Bs[128 * PK];
  int tid = threadIdx.x;
  int lane = tid & 63, w = tid >> 6;
  int wm = w & 1, wn = w >> 1;
  int col16 = lane & 15, quad = lane >> 4;
  int row0 = blockIdx.y * 128, col0 = blockIdx.x * 128;
  const unsigned short* Ag = (const unsigned short*)A;
  const unsigned short* Bg = (const unsigned short*)Bt;

  f32x4 acc[4][4] = {};

  for (int k0 = 0; k0 < K; k0 += 32) {
#pragma unroll
    for (int c = tid; c < 512; c += 256) {
      int r = c >> 2, ko = (c & 3) << 3;
      int gr = row0 + r;
      if (gr >= M) gr = M - 1;
      ushort8 v = *(const ushort8*)(Ag + (size_t)gr * K + k0 + ko);
      *(ushort8*)(&As[r * PK + ko]) = v;
    }
#pragma unroll
    for (int c = tid; c < 512; c += 256) {
      int r = c >> 2, ko = (c & 3) << 3;
      int gc = col0 + r;
      if (gc >= N) gc = N - 1;
      ushort8 v = *(const ushort8*)(Bg + (size_t)gc * K + k0 + ko);
      *(ushort8*)(&Bs[r * PK + ko]) = v;
    }
    __syncthreads();
    bf16x8 a[4], b[4];
#pragma unroll
    for (int i = 0; i < 4; i++)
      a[i] = *(const bf16x8*)(&As[(wm * 64 + i * 16 + col16) * PK + quad * 8]);
#pragma unroll
    for (int j = 0; j < 4; j++)
      b[j] = *(const bf16x8*)(&Bs[(wn * 64 + j * 16 + col16) * PK + quad * 8]);
#pragma unroll
    for (int i = 0; i < 4; i++)
#pragma unroll
      for (int j = 0; j < 4; j++)
        acc[i][j] = __builtin_amdgcn_mfma_f32_16x16x32_bf16(a[i], b[j], acc[i][j], 0, 0, 0);
    __syncthreads();
  }

#pragma unroll
  for (int i = 0; i < 4; i++) {
#pragma unroll
    for (int j = 0; j < 4; j++) {
      int gc = col0 + wn * 64 + j * 16 + col16;
      if (gc >= N) continue;
      int grb = row0 + wm * 64 + i * 16 + quad * 4;
      float bv = bias ? bias[gc] : 0.f;
#pragma unroll
      for (int r = 0; r < 4; r++) {
        int gr = grb + r;
        if (gr >= M) continue;
        float v = acc[i][j][r] + bv;
        if (act == 2) v = 1.f / (1.f + __expf(-v));
        if (Cb) Cb[(size_t)gr * N + gc] = __float2bfloat16(v);
        else Cf[(size_t)gr * N + gc] = v;
      }
    }
  }
}

// ---------------------------------------------------------------------------
// casts / weight prep (fused: W1t, W2t, Wm1t, Wm2t transposes)
// ---------------------------------------------------------------------------
__global__ void cast_bf16(const float* __restrict__ src, __hip_bfloat16* __restrict__ dst, int count) {
  int i = blockIdx.x * 256 + threadIdx.x;
  if (i < count) dst[i] = __float2bfloat16(src[i]);
}

__global__ void prep_weights(const float* __restrict__ W1, const float* __restrict__ W2,
                             const float* __restrict__ Wm1, const float* __restrict__ Wm2,
                             __hip_bfloat16* __restrict__ W1t, __hip_bfloat16* __restrict__ W2t,
                             __hip_bfloat16* __restrict__ Wm1t, __hip_bfloat16* __restrict__ Wm2t) {
  int i = blockIdx.x * 256 + threadIdx.x;
  if (i < 128 * 256) {  // W1: K=128, N=256
    int nn = i / 128, kk = i - nn * 128;
    W1t[i] = __float2bfloat16(W1[(size_t)kk * 256 + nn]);
    return;
  }
  i -= 128 * 256;
  if (i < 256 * 256) {  // W2: K=256, N=256
    int nn = i / 256, kk = i - nn * 256;
    W2t[i] = __float2bfloat16(W2[(size_t)kk * 256 + nn]);
    return;
  }
  i -= 256 * 256;
  if (i < 256 * 64) {   // Wm1: K=256, N=64
    int nn = i / 256, kk = i - nn * 256;
    Wm1t[i] = __float2bfloat16(Wm1[(size_t)kk * 64 + nn]);
    return;
  }
  i -= 256 * 64;
  if (i < 64 * 121) {   // Wm2: K=64, N=121
    int nn = i / 64, kk = i - nn * 64;
    Wm2t[i] = __float2bfloat16(Wm2[(size_t)kk * 121 + nn]);
  }
}

// ---------------------------------------------------------------------------
// Attention coefficients from bf16 h
// ---------------------------------------------------------------------------
__global__ void attn_coef(const __hip_bfloat16* __restrict__ h,
                          const float* __restrict__ att_s,
                          const float* __restrict__ att_d,
                          float* __restrict__ a_s, float* __restrict__ a_d,
                          int n) {
  int idx = blockIdx.x * 256 + threadIdx.x;
  if (idx >= n * HEADS) return;
  int node = idx >> 2, hd = idx & 3;
  const uint4* hp = (const uint4*)((const unsigned short*)h + (size_t)node * HC + hd * HID);
  const float* wsv = att_s + hd * HID;
  const float* wdv = att_d + hd * HID;
  float ss = 0.f, sd = 0.f;
#pragma unroll
  for (int i = 0; i < 8; i++) {
    uint4 u = hp[i];
    float f[8] = {bflo(u.x), bfhi(u.x), bflo(u.y), bfhi(u.y),
                  bflo(u.z), bfhi(u.z), bflo(u.w), bfhi(u.w)};
#pragma unroll
    for (int j = 0; j < 8; j++) {
      int c = i * 8 + j;
      ss += f[j] * wsv[c];
      sd += f[j] * wdv[c];
    }
  }
  a_s[idx] = ss;
  a_d[idx] = sd;
}

// ---------------------------------------------------------------------------
// CSR build
// ---------------------------------------------------------------------------
__global__ void deg_init(int* __restrict__ deg, int n) {
  int i = blockIdx.x * 256 + threadIdx.x;
  if (i < n) deg[i] = 1;
}

__global__ void deg_count(const int* __restrict__ ei, int E, int* __restrict__ deg) {
  int i = blockIdx.x * 256 + threadIdx.x;
  if (i < E) atomicAdd(&deg[ei[E + i]], 1);
}

__global__ void __launch_bounds__(256) scan_block(const int* __restrict__ deg,
                                                  int* __restrict__ row_start,
                                                  int* __restrict__ bsum, int n) {
  __shared__ int wt[4];
  int tid = threadIdx.x, lane = tid & 63, w = tid >> 6;
  int i = blockIdx.x * 256 + tid;
  int v = (i < n) ? deg[i] : 0;
  int s = v;
#pragma unroll
  for (int off = 1; off < 64; off <<= 1) {
    int t = __shfl_up(s, off);
    if (lane >= off) s += t;
  }
  if (lane == 63) wt[w] = s;
  __syncthreads();
  int add = 0;
  if (w > 0) add += wt[0];
  if (w > 1) add += wt[1];
  if (w > 2) add += wt[2];
  if (i < n) row_start[i + 1] = s + add;
  if (tid == 0) bsum[blockIdx.x] = wt[0] + wt[1] + wt[2] + wt[3];
}

__global__ void __launch_bounds__(256) scan_partials(int* __restrict__ bsum, int nb) {
  __shared__ int wt[4];
  int tid = threadIdx.x, lane = tid & 63, w = tid >> 6;
  int v = (tid < nb) ? bsum[tid] : 0;
  int s = v;
#pragma unroll
  for (int off = 1; off < 64; off <<= 1) {
    int t = __shfl_up(s, off);
    if (lane >= off) s += t;
  }
  if (lane == 63) wt[w] = s;
  __syncthreads();
  int add = 0;
  if (w > 0) add += wt[0];
  if (w > 1) add += wt[1];
  if (w > 2) add += wt[2];
  if (tid < nb) bsum[tid] = s + add - v;
}

__global__ void finalize_row(int* __restrict__ row_start, const int* __restrict__ bsum_ex,
                             const int* __restrict__ deg, int* __restrict__ cur, int n) {
  int i = blockIdx.x * 256 + threadIdx.x;
  if (i == 0) row_start[0] = 0;
  if (i < n) {
    int v = row_start[i + 1] + bsum_ex[blockIdx.x];
    row_start[i + 1] = v;
    cur[i] = v - deg[i];
  }
}

__global__ void csr_fill(const int* __restrict__ ei, int E, int n,
                         int* __restrict__ cur, int* __restrict__ csr_src) {
  int i = blockIdx.x * 256 + threadIdx.x;
  int Etot = E + n;
  if (i >= Etot) return;
  int s, d;
  if (i < E) { s = ei[i]; d = ei[E + i]; }
  else { s = d = i - E; }
  int pos = atomicAdd(&cur[d], 1);
  csr_src[pos] = s;
}

// ---------------------------------------------------------------------------
// GAT aggregation, lane-parallel edges + broadcast accumulation.
// One wave per dst node. Per 64-edge chunk: lane i handles edge beg+i
// (coalesced index load, coef gather, 4 logits + 4 exps), wave max-reduce,
// softmax weights stashed in LDS. Accumulation loop: edge index via
// readlane (scalar base gather), weight via 1-dword LDS broadcast; lane t
// owns channels 4t..4t+3 -> one dwordx2 gather per edge. Unrolled x4.
// ---------------------------------------------------------------------------
__global__ void __launch_bounds__(256) gat_aggregate(
    const __hip_bfloat16* __restrict__ hb, const float* __restrict__ a_src,
    const float* __restrict__ a_dst, const int* __restrict__ row_start,
    const int* __restrict__ csr_src, const float* __restrict__ bias,
    __hip_bfloat16* __restrict__ out, int n) {
  __shared__ float plds[4][256];
  int wid = threadIdx.x >> 6;
  int lane = threadIdx.x & 63;
  int qh = lane >> 4;  // head owned by this lane's channels (4*lane..4*lane+3)
  int node = (blockIdx.x << 2) + wid;
  if (node >= n) return;
  float4 adv = *(const float4*)(a_dst + (size_t)node * 4);
  int beg = __builtin_amdgcn_readfirstlane(row_start[node]);
  int end = __builtin_amdgcn_readfirstlane(row_start[node + 1]);
  const unsigned* hw = (const unsigned*)hb;

  float m0 = -FLT_MAX, m1 = -FLT_MAX, m2 = -FLT_MAX, m3 = -FLT_MAX;
  float lq = 0.f, cq0 = 0.f, cq1 = 0.f, cq2 = 0.f, cq3 = 0.f;

  for (int cbeg = beg; cbeg < end; cbeg += 64) {
    int cnt = end - cbeg; if (cnt > 64) cnt = 64;
    bool valid = lane < cnt;
    int eidx = cbeg + (valid ? lane : cnt - 1);
    int s_l = csr_src[eidx];
    float4 as = *(const float4*)(a_src + (size_t)s_l * 4);
    float v0 = as.x + adv.x; v0 = fmaxf(v0, NEG_SLOPE * v0);
    float v1 = as.y + adv.y; v1 = fmaxf(v1, NEG_SLOPE * v1);
    float v2 = as.z + adv.z; v2 = fmaxf(v2, NEG_SLOPE * v2);
    float v3 = as.w + adv.w; v3 = fmaxf(v3, NEG_SLOPE * v3);
    if (!valid) { v0 = v1 = v2 = v3 = -FLT_MAX; }
    // wave max per head
    float x0 = v0, x1 = v1, x2 = v2, x3 = v3;
#pragma unroll
    for (int off = 32; off; off >>= 1) {
      x0 = fmaxf(x0, __shfl_xor(x0, off));
      x1 = fmaxf(x1, __shfl_xor(x1, off));
      x2 = fmaxf(x2, __shfl_xor(x2, off));
      x3 = fmaxf(x3, __shfl_xor(x3, off));
    }
    float nm0 = fmaxf(m0, x0), nm1 = fmaxf(m1, x1);
    float nm2 = fmaxf(m2, x2), nm3 = fmaxf(m3, x3);
    // rescale running accum (first chunk: exp(-inf)=0 * zero accum = 0)
    float mo = (qh < 2) ? (qh == 0 ? m0 : m1) : (qh == 2 ? m2 : m3);
    float mn = (qh < 2) ? (qh == 0 ? nm0 : nm1) : (qh == 2 ? nm2 : nm3);
    float scq = __expf(mo - mn);
    lq *= scq; cq0 *= scq; cq1 *= scq; cq2 *= scq; cq3 *= scq;
    m0 = nm0; m1 = nm1; m2 = nm2; m3 = nm3;
    // softmax numerators for this lane's edge (invalid lanes -> 0)
    float p0 = __expf(v0 - nm0), p1 = __expf(v1 - nm1);
    float p2 = __expf(v2 - nm2), p3 = __expf(v3 - nm3);
    *(float4*)&plds[wid][lane * 4] = make_float4(p0, p1, p2, p3);
    __builtin_amdgcn_s_waitcnt(0);  // ensure ds_write visible to our ds_reads

    auto step = [&](int jj) {
      int sj = __builtin_amdgcn_readlane(s_l, jj);
      float pq = plds[wid][jj * 4 + qh];
      uint2 d = *(const uint2*)(hw + (size_t)sj * 128 + 2 * lane);
      cq0 += pq * bflo(d.x); cq1 += pq * bfhi(d.x);
      cq2 += pq * bflo(d.y); cq3 += pq * bfhi(d.y);
      lq += pq;
    };
    int j = 0;
    for (; j + 4 <= cnt; j += 4) { step(j); step(j + 1); step(j + 2); step(j + 3); }
    for (; j < cnt; ++j) step(j);
  }

  float4 bq = *(const float4*)(bias + 4 * lane);
  float rq = 1.f / (lq + EPS);
  float o0 = fmaxf(cq0 * rq + bq.x, 0.f);
  float o1 = fmaxf(cq1 * rq + bq.y, 0.f);
  float o2 = fmaxf(cq2 * rq + bq.z, 0.f);
  float o3 = fmaxf(cq3 * rq + bq.w, 0.f);
  uint2 pk;
  pk.x = packbf2(o0, o1);
  pk.y = packbf2(o2, o3);
  *(uint2*)((unsigned*)out + (size_t)node * 128 + 2 * lane) = pk;
}

// ---------------------------------------------------------------------------
extern "C" void kernel_launch(void* const* d_in, const int* in_sizes, int n_in,
                              void* d_out, int out_size, void* d_ws, size_t ws_size,
                              hipStream_t stream) {
  const float* x      = (const float*)d_in[0];
  const int*   ei     = (const int*)d_in[1];
  const float* W1     = (const float*)d_in[2];
  const float* att_s1 = (const float*)d_in[3];
  const float* att_d1 = (const float*)d_in[4];
  const float* b1     = (const float*)d_in[5];
  const float* W2     = (const float*)d_in[6];
  const float* att_s2 = (const float*)d_in[7];
  const float* att_d2 = (const float*)d_in[8];
  const float* b2     = (const float*)d_in[9];
  const float* Wm1    = (const float*)d_in[10];
  const float* bm1    = (const float*)d_in[11];
  const float* Wm2    = (const float*)d_in[12];
  const float* bm2    = (const float*)d_in[13];
  float* out = (float*)d_out;

  int n = in_sizes[0] / 128;   // 50000
  int E = in_sizes[1] / 2;     // 800000
  int Etot = E + n;

  char* ws = (char*)d_ws;
  size_t off = 0;
  auto carve = [&](size_t bytes) {
    char* p = ws + off;
    off += (bytes + 255) & ~(size_t)255;
    return p;
  };
  __hip_bfloat16* hb   = (__hip_bfloat16*)carve((size_t)n * HC * 2);
  __hip_bfloat16* aggb = (__hip_bfloat16*)carve((size_t)n * HC * 2);
  __hip_bfloat16* xb   = (__hip_bfloat16*)carve((size_t)n * 128 * 2);
  __hip_bfloat16* pm1b = (__hip_bfloat16*)carve((size_t)n * HID * 2);
  __hip_bfloat16* W1t  = (__hip_bfloat16*)carve((size_t)128 * HC * 2);
  __hip_bfloat16* W2t  = (__hip_bfloat16*)carve((size_t)HC * HC * 2);
  __hip_bfloat16* Wm1t = (__hip_bfloat16*)carve((size_t)HC * HID * 2);
  __hip_bfloat16* Wm2t = (__hip_bfloat16*)carve((size_t)HID * 121 * 2);
  float* as   = (float*)carve((size_t)n * HEADS * 4);
  float* ad   = (float*)carve((size_t)n * HEADS * 4);
  int*   deg  = (int*)carve((size_t)n * 4);
  int*   row  = (int*)carve((size_t)(n + 1) * 4);
  int*   cur  = (int*)carve((size_t)n * 4);
  int*   csr  = (int*)carve((size_t)Etot * 4);
  int*   bsum = (int*)carve((size_t)1024 * 4);
  (void)ws_size;

  int nb256 = (n + 255) / 256;
  int rows128 = (n + 127) / 128;

  // --- input casts / weight prep ---
  cast_bf16<<<(n * 128 + 255) / 256, 256, 0, stream>>>(x, xb, n * 128);
  prep_weights<<<(122432 + 255) / 256, 256, 0, stream>>>(W1, W2, Wm1, Wm2, W1t, W2t, Wm1t, Wm2t);

  // --- CSR build ---
  deg_init<<<nb256, 256, 0, stream>>>(deg, n);
  deg_count<<<(E + 255) / 256, 256, 0, stream>>>(ei, E, deg);
  scan_block<<<nb256, 256, 0, stream>>>(deg, row, bsum, n);
  scan_partials<<<1, 256, 0, stream>>>(bsum, nb256);
  finalize_row<<<nb256, 256, 0, stream>>>(row, bsum, deg, cur, n);
  csr_fill<<<(Etot + 255) / 256, 256, 0, stream>>>(ei, E, n, cur, csr);

  // --- conv1 ---
  mfma_gemm<<<dim3(2, rows128), 256, 0, stream>>>(xb, W1t, nullptr, nullptr, hb, n, HC, 128, 0);
  attn_coef<<<(n * HEADS + 255) / 256, 256, 0, stream>>>(hb, att_s1, att_d1, as, ad, n);
  gat_aggregate<<<(n + 3) / 4, 256, 0, stream>>>(hb, as, ad, row, csr, b1, aggb, n);

  // --- conv2 ---
  mfma_gemm<<<dim3(2, rows128), 256, 0, stream>>>(aggb, W2t, nullptr, nullptr, hb, n, HC, HC, 0);
  attn_coef<<<(n * HEADS + 255) / 256, 256, 0, stream>>>(hb, att_s2, att_d2, as, ad, n);
  gat_aggregate<<<(n + 3) / 4, 256, 0, stream>>>(hb, as, ad, row, csr, b2, aggb, n);

  // --- post_mp ---
  mfma_gemm<<<dim3(1, rows128), 256, 0, stream>>>(aggb, Wm1t, bm1, nullptr, pm1b, n, HID, HC, 0);
  mfma_gemm<<<dim3(1, rows128), 256, 0, stream>>>(pm1b, Wm2t, bm2, out, nullptr, n, 121, HID, 2);
}